// Round 2
// 11236.311 us; speedup vs baseline: 1.4925x; 1.4925x over previous
//
#include <hip/hip_runtime.h>
#include <math.h>

#define T_STEPS 1000
#define BATCH   64
#define INSZ    700
#define NH      1000

// ---------------------------------------------------------------------------
// Kernel A: Z = X @ Win^T + bias  → written straight into d_out  (unchanged)
// ---------------------------------------------------------------------------
#define TM 64
#define TN 64
#define TK 16

__global__ __launch_bounds__(256) void proj_kernel(
    const float* __restrict__ A, const float* __restrict__ Bw,
    const float* __restrict__ bias, float* __restrict__ C)
{
    __shared__ float As[TK][68];
    __shared__ float Bs[TK][68];

    const int tid = threadIdx.x;
    const int tx  = tid & 15;
    const int ty  = tid >> 4;
    const int m0  = blockIdx.y * TM;
    const int n0  = blockIdx.x * TN;

    const int lr = tid >> 2;
    const int lk = (tid & 3) * 4;

    float acc[4][4] = {};

    for (int k0 = 0; k0 < INSZ; k0 += TK) {
        float4 av = make_float4(0.f, 0.f, 0.f, 0.f);
        if (k0 + lk < INSZ)
            av = *(const float4*)(A + (size_t)(m0 + lr) * INSZ + k0 + lk);
        As[lk + 0][lr] = av.x; As[lk + 1][lr] = av.y;
        As[lk + 2][lr] = av.z; As[lk + 3][lr] = av.w;

        float4 bv = make_float4(0.f, 0.f, 0.f, 0.f);
        if ((n0 + lr) < NH && (k0 + lk) < INSZ)
            bv = *(const float4*)(Bw + (size_t)(n0 + lr) * INSZ + k0 + lk);
        Bs[lk + 0][lr] = bv.x; Bs[lk + 1][lr] = bv.y;
        Bs[lk + 2][lr] = bv.z; Bs[lk + 3][lr] = bv.w;

        __syncthreads();

        #pragma unroll
        for (int k = 0; k < TK; ++k) {
            float4 a4 = *(const float4*)&As[k][ty * 4];
            float4 b4 = *(const float4*)&Bs[k][tx * 4];
            float a[4] = {a4.x, a4.y, a4.z, a4.w};
            float b[4] = {b4.x, b4.y, b4.z, b4.w};
            #pragma unroll
            for (int i = 0; i < 4; ++i)
                #pragma unroll
                for (int j = 0; j < 4; ++j)
                    acc[i][j] += a[i] * b[j];
        }
        __syncthreads();
    }

    #pragma unroll
    for (int i = 0; i < 4; ++i) {
        const int m = m0 + ty * 4 + i;
        #pragma unroll
        for (int j = 0; j < 4; ++j) {
            const int n = n0 + tx * 4 + j;
            if (n < NH)
                C[(size_t)m * NH + n] = acc[i][j] + bias[n];
        }
    }
}

// ---------------------------------------------------------------------------
// Kernel B: persistent cooperative recurrence.
//
// 8 clusters (b-groups of 8 rows) x 32 WGs (n-slices of 32 cols). Each WG
// keeps its Wlsm slice (1000x32 f32 = 125 KiB) resident in LDS for all 1000
// steps. Per step: 16-way split-k, each thread = (b-pair, n-quad, k-stride):
// per k-quad 1 ds_read_b128 + 2 broadcast h float4 + 32 FMA (FMA-bound).
// LDS reduce over the 16 k-partials, tanh, in-place store over Z.
// Per-cluster monotonic barrier: agent-scope atomicAdd (release) + spin +
// one acquire fence; clusters are independent and drift freely.
// cluster = blockIdx.x & 7 so default round-robin keeps a cluster on 1 XCD.
// ---------------------------------------------------------------------------
#define NSL     32
#define SLICES  32
#define NCLUST  8
#define BG      8
#define PTH     512

#define RANK1(acc, s, vv)                                    \
    acc[0] += (s) * (vv).x; acc[1] += (s) * (vv).y;          \
    acc[2] += (s) * (vv).z; acc[3] += (s) * (vv).w;

__global__ __launch_bounds__(512) void lsm_persist(
    const float* __restrict__ Wl,      // (N, N) row-major
    float* __restrict__ out,           // (T, B, N): in Z, out h (in-place)
    unsigned* __restrict__ counters)   // 8 clusters x 64 uints (zeroed)
{
    __shared__ float Wlds[NH * NSL];          // 125 KiB
    __shared__ float red[16][4][8][12];       // 24 KiB (pad 12 -> bank-spread)

    const int tid     = threadIdx.x;
    const int cluster = blockIdx.x & 7;
    const int slice   = blockIdx.x >> 3;
    const int n0      = slice * NSL;
    const int wid     = (NH - n0 < NSL) ? (NH - n0) : NSL;   // 32, last slice 8

    // ---- one-time: stage W columns [n0, n0+wid) into LDS ----
    if (wid < NSL) {   // zero the unused tail so stray FMAs stay finite-dead
        const float4 z4 = make_float4(0.f, 0.f, 0.f, 0.f);
        for (int i = tid; i < NH * NSL / 4; i += PTH)
            *(float4*)&Wlds[i * 4] = z4;
        __syncthreads();
    }
    {
        const int qsh   = (wid == NSL) ? 3 : 1;   // float4-quads per row: 8 or 2
        const int qmask = (1 << qsh) - 1;
        const int total = NH << qsh;
        for (int i = tid; i < total; i += PTH) {
            const int r = i >> qsh;
            const int q = i & qmask;
            *(float4*)&Wlds[r * NSL + (q << 2)] =
                *(const float4*)(Wl + (size_t)r * NH + n0 + (q << 2));
        }
    }
    __syncthreads();

    // k-loop mapping: wave = 8 nq x 4 bp x 2 sk  (broadcast-friendly)
    const int nq = tid & 7;           // n-quad 0..7  -> cols nq*4..+3
    const int bp = (tid >> 3) & 3;    // b-pair 0..3  -> rows 2bp, 2bp+1
    const int sk = tid >> 5;          // split-k 0..15 (stride-16 over k-quads)
    const int b0 = cluster * BG + bp * 2;

    // output mapping (threads 0..255): 8 b x 32 n
    const int on  = tid & 31;
    const int ob  = tid >> 5;                       // valid when tid < 256
    const bool owrite = (tid < 256) && (n0 + on < NH);
    const size_t oidx = (size_t)(cluster * BG + (ob & 7)) * NH + n0 + on;

    unsigned* cnt = counters + cluster * 64;        // 256 B apart per cluster

    for (int t = 0; t < T_STEPS; ++t) {
        float* zrow = out + (size_t)t * (BATCH * NH);
        float zval = 0.f;
        if (owrite) zval = zrow[oidx];              // issued early, used late

        float sum = 0.f;
        if (t > 0) {
            const float* hb0 = out + (size_t)(t - 1) * (BATCH * NH)
                                   + (size_t)b0 * NH;
            const float* hb1 = hb0 + NH;
            float a0[4] = {0.f, 0.f, 0.f, 0.f};
            float a1[4] = {0.f, 0.f, 0.f, 0.f};

            #pragma unroll 4
            for (int q = sk; q < 250; q += 16) {    // k-quad, k = 4q
                const int k = q << 2;
                const float4 ha = *(const float4*)(hb0 + k);
                const float4 hc = *(const float4*)(hb1 + k);
                const float4 w0 = *(const float4*)&Wlds[(k + 0) * NSL + (nq << 2)];
                const float4 w1 = *(const float4*)&Wlds[(k + 1) * NSL + (nq << 2)];
                const float4 w2 = *(const float4*)&Wlds[(k + 2) * NSL + (nq << 2)];
                const float4 w3 = *(const float4*)&Wlds[(k + 3) * NSL + (nq << 2)];
                RANK1(a0, ha.x, w0) RANK1(a0, ha.y, w1)
                RANK1(a0, ha.z, w2) RANK1(a0, ha.w, w3)
                RANK1(a1, hc.x, w0) RANK1(a1, hc.y, w1)
                RANK1(a1, hc.z, w2) RANK1(a1, hc.w, w3)
            }

            *(float4*)&red[sk][bp][nq][0] = make_float4(a0[0], a0[1], a0[2], a0[3]);
            *(float4*)&red[sk][bp][nq][4] = make_float4(a1[0], a1[1], a1[2], a1[3]);
            __syncthreads();

            if (tid < 256) {
                const int rb = ob >> 1;
                const int rq = on >> 2;
                const int rm = (ob & 1) * 4 + (on & 3);
                #pragma unroll
                for (int s = 0; s < 16; ++s)
                    sum += red[s][rb][rq][rm];
            }
        }

        if (owrite) zrow[oidx] = tanhf(zval + sum);

        if (t + 1 < T_STEPS) {
            __syncthreads();   // drains vmcnt: all h stores at least in L2
            if (tid == 0) {
                __hip_atomic_fetch_add(cnt, 1u, __ATOMIC_RELEASE,
                                       __HIP_MEMORY_SCOPE_AGENT);
                const unsigned tgt = (unsigned)(t + 1) * SLICES;
                while (__hip_atomic_load(cnt, __ATOMIC_RELAXED,
                                         __HIP_MEMORY_SCOPE_AGENT) < tgt) {}
                __builtin_amdgcn_fence(__ATOMIC_ACQUIRE, "agent");
            }
            __syncthreads();
        }
    }
}

// ---------------------------------------------------------------------------
extern "C" void kernel_launch(void* const* d_in, const int* in_sizes, int n_in,
                              void* d_out, int out_size, void* d_ws, size_t ws_size,
                              hipStream_t stream) {
    const float* x    = (const float*)d_in[0];  // (T, B, INSZ)
    const float* Win  = (const float*)d_in[1];  // (N, INSZ)
    const float* bias = (const float*)d_in[2];  // (N,)
    const float* Wlsm = (const float*)d_in[3];  // (N, N)
    float* out    = (float*)d_out;              // (T, B, N)
    unsigned* cnt = (unsigned*)d_ws;

    // Phase 1: input projection for all timesteps at once
    proj_kernel<<<dim3(16, (T_STEPS * BATCH) / TM), 256, 0, stream>>>(x, Win, bias, out);

    // Phase 2: single persistent cooperative kernel for all 1000 steps
    (void)hipMemsetAsync(d_ws, 0, NCLUST * 64 * sizeof(unsigned), stream);
    void* args[] = { (void*)&Wlsm, (void*)&out, (void*)&cnt };
    (void)hipLaunchCooperativeKernel((void*)lsm_persist,
                                     dim3(NCLUST * SLICES), dim3(PTH),
                                     args, 0, stream);
}

// Round 3
// 6306.574 us; speedup vs baseline: 2.6591x; 1.7817x over previous
//
#include <hip/hip_runtime.h>
#include <math.h>

#define T_STEPS 1000
#define BATCH   64
#define INSZ    700
#define NH      1000

// ---------------------------------------------------------------------------
// Kernel A: Z = X @ Win^T + bias  → written straight into d_out  (unchanged)
// ---------------------------------------------------------------------------
#define TM 64
#define TN 64
#define TK 16

__global__ __launch_bounds__(256) void proj_kernel(
    const float* __restrict__ A, const float* __restrict__ Bw,
    const float* __restrict__ bias, float* __restrict__ C)
{
    __shared__ float As[TK][68];
    __shared__ float Bs[TK][68];

    const int tid = threadIdx.x;
    const int tx  = tid & 15;
    const int ty  = tid >> 4;
    const int m0  = blockIdx.y * TM;
    const int n0  = blockIdx.x * TN;

    const int lr = tid >> 2;
    const int lk = (tid & 3) * 4;

    float acc[4][4] = {};

    for (int k0 = 0; k0 < INSZ; k0 += TK) {
        float4 av = make_float4(0.f, 0.f, 0.f, 0.f);
        if (k0 + lk < INSZ)
            av = *(const float4*)(A + (size_t)(m0 + lr) * INSZ + k0 + lk);
        As[lk + 0][lr] = av.x; As[lk + 1][lr] = av.y;
        As[lk + 2][lr] = av.z; As[lk + 3][lr] = av.w;

        float4 bv = make_float4(0.f, 0.f, 0.f, 0.f);
        if ((n0 + lr) < NH && (k0 + lk) < INSZ)
            bv = *(const float4*)(Bw + (size_t)(n0 + lr) * INSZ + k0 + lk);
        Bs[lk + 0][lr] = bv.x; Bs[lk + 1][lr] = bv.y;
        Bs[lk + 2][lr] = bv.z; Bs[lk + 3][lr] = bv.w;

        __syncthreads();

        #pragma unroll
        for (int k = 0; k < TK; ++k) {
            float4 a4 = *(const float4*)&As[k][ty * 4];
            float4 b4 = *(const float4*)&Bs[k][tx * 4];
            float a[4] = {a4.x, a4.y, a4.z, a4.w};
            float b[4] = {b4.x, b4.y, b4.z, b4.w};
            #pragma unroll
            for (int i = 0; i < 4; ++i)
                #pragma unroll
                for (int j = 0; j < 4; ++j)
                    acc[i][j] += a[i] * b[j];
        }
        __syncthreads();
    }

    #pragma unroll
    for (int i = 0; i < 4; ++i) {
        const int m = m0 + ty * 4 + i;
        #pragma unroll
        for (int j = 0; j < 4; ++j) {
            const int n = n0 + tx * 4 + j;
            if (n < NH)
                C[(size_t)m * NH + n] = acc[i][j] + bias[n];
        }
    }
}

// ---------------------------------------------------------------------------
// Kernel B: persistent cooperative recurrence.
//
// 8 clusters (b-groups of 8 rows) x 32 WGs (n-slices of 32 cols); Wlsm slice
// resident in LDS for all 1000 steps.
//
// Exchange protocol (per-access coherence; NO agent release/acquire fences,
// which on gfx950 emit buffer_wbl2 / buffer_inv = full L2 drain+invalidate
// per step — that was 87% stall in R2):
//   * Z-preload and h-store are relaxed agent-scope scalar atomics
//     (sc0+sc1: bypass L1/L2, write through to L3). So no h address ever
//     has a stale L1/L2 copy anywhere — the only pre-store reader bypassed
//     the caches, and the store writes through.
//   * Hence k-loop h-loads are PLAIN cached float4 loads: first touch in
//     any L1/L2, filled from L3 (the coherence point) which is fresh.
//   * Counter: relaxed atomics only; store→flag ordering via the vmcnt(0)
//     drain implied by __syncthreads (+ explicit s_waitcnt belt-and-braces).
// Placement-independent: correctness never depends on WG→XCD assignment.
// ---------------------------------------------------------------------------
#define NSL     32
#define SLICES  32
#define NCLUST  8
#define BG      8
#define PTH     512

#define RANK1(acc, s, vv)                                    \
    acc[0] += (s) * (vv).x; acc[1] += (s) * (vv).y;          \
    acc[2] += (s) * (vv).z; acc[3] += (s) * (vv).w;

__global__ __launch_bounds__(512) void lsm_persist(
    const float* __restrict__ Wl,      // (N, N) row-major
    float* __restrict__ out,           // (T, B, N): in Z, out h (in-place)
    unsigned* __restrict__ counters)   // 8 clusters x 64 uints (zeroed)
{
    __shared__ float Wlds[NH * NSL];          // 125 KiB
    __shared__ float red[16][4][8][12];       // 24 KiB (pad 12 -> bank-spread)

    const int tid     = threadIdx.x;
    const int cluster = blockIdx.x & 7;
    const int slice   = blockIdx.x >> 3;
    const int n0      = slice * NSL;
    const int wid     = (NH - n0 < NSL) ? (NH - n0) : NSL;   // 32, last slice 8

    // ---- one-time: stage W columns [n0, n0+wid) into LDS ----
    if (wid < NSL) {   // zero the unused tail so stray FMAs stay finite-dead
        const float4 z4 = make_float4(0.f, 0.f, 0.f, 0.f);
        for (int i = tid; i < NH * NSL / 4; i += PTH)
            *(float4*)&Wlds[i * 4] = z4;
        __syncthreads();
    }
    {
        const int qsh   = (wid == NSL) ? 3 : 1;   // float4-quads per row: 8 or 2
        const int qmask = (1 << qsh) - 1;
        const int total = NH << qsh;
        for (int i = tid; i < total; i += PTH) {
            const int r = i >> qsh;
            const int q = i & qmask;
            *(float4*)&Wlds[r * NSL + (q << 2)] =
                *(const float4*)(Wl + (size_t)r * NH + n0 + (q << 2));
        }
    }
    __syncthreads();

    // k-loop mapping: wave = 8 nq x 4 bp x 2 sk  (broadcast-friendly)
    const int nq = tid & 7;           // n-quad 0..7  -> cols nq*4..+3
    const int bp = (tid >> 3) & 3;    // b-pair 0..3  -> rows 2bp, 2bp+1
    const int sk = tid >> 5;          // split-k 0..15 (stride-16 over k-quads)
    const int b0 = cluster * BG + bp * 2;

    // output mapping (threads 0..255): 8 b x 32 n
    const int on  = tid & 31;
    const int ob  = tid >> 5;                       // valid when tid < 256
    const bool owrite = (tid < 256) && (n0 + on < NH);
    const size_t oidx = (size_t)(cluster * BG + (ob & 7)) * NH + n0 + on;

    unsigned* cnt = counters + cluster * 64;        // 256 B apart per cluster

    for (int t = 0; t < T_STEPS; ++t) {
        float* zrow = out + (size_t)t * (BATCH * NH);
        float zval = 0.f;
        if (owrite)   // sc0+sc1 load: no L1/L2 allocation → no stale copy later
            zval = __hip_atomic_load(&zrow[oidx], __ATOMIC_RELAXED,
                                     __HIP_MEMORY_SCOPE_AGENT);

        float sum = 0.f;
        if (t > 0) {
            const float* hb0 = out + (size_t)(t - 1) * (BATCH * NH)
                                   + (size_t)b0 * NH;
            const float* hb1 = hb0 + NH;
            float a0[4] = {0.f, 0.f, 0.f, 0.f};
            float a1[4] = {0.f, 0.f, 0.f, 0.f};

            #pragma unroll 8
            for (int q = sk; q < 250; q += 16) {    // k-quad, k = 4q
                const int k = q << 2;
                const float4 ha = *(const float4*)(hb0 + k);
                const float4 hc = *(const float4*)(hb1 + k);
                const float4 w0 = *(const float4*)&Wlds[(k + 0) * NSL + (nq << 2)];
                const float4 w1 = *(const float4*)&Wlds[(k + 1) * NSL + (nq << 2)];
                const float4 w2 = *(const float4*)&Wlds[(k + 2) * NSL + (nq << 2)];
                const float4 w3 = *(const float4*)&Wlds[(k + 3) * NSL + (nq << 2)];
                RANK1(a0, ha.x, w0) RANK1(a0, ha.y, w1)
                RANK1(a0, ha.z, w2) RANK1(a0, ha.w, w3)
                RANK1(a1, hc.x, w0) RANK1(a1, hc.y, w1)
                RANK1(a1, hc.z, w2) RANK1(a1, hc.w, w3)
            }

            *(float4*)&red[sk][bp][nq][0] = make_float4(a0[0], a0[1], a0[2], a0[3]);
            *(float4*)&red[sk][bp][nq][4] = make_float4(a1[0], a1[1], a1[2], a1[3]);
            __syncthreads();

            if (tid < 256) {
                const int rb = ob >> 1;
                const int rq = on >> 2;
                const int rm = (ob & 1) * 4 + (on & 3);
                #pragma unroll
                for (int s = 0; s < 16; ++s)
                    sum += red[s][rb][rq][rm];
            }
        }

        if (owrite) {  // sc0+sc1 store: write-through to L3 (coherence point)
            const float hv = tanhf(zval + sum);
            __hip_atomic_store(&zrow[oidx], hv, __ATOMIC_RELAXED,
                               __HIP_MEMORY_SCOPE_AGENT);
        }

        if (t + 1 < T_STEPS) {
            // drain this wave's stores before signalling (syncthreads also
            // drains vmcnt in every wave — this is belt-and-braces)
            asm volatile("s_waitcnt vmcnt(0)" ::: "memory");
            __syncthreads();
            if (tid == 0) {
                __hip_atomic_fetch_add(cnt, 1u, __ATOMIC_RELAXED,
                                       __HIP_MEMORY_SCOPE_AGENT);
                const unsigned tgt = (unsigned)(t + 1) * SLICES;
                while (__hip_atomic_load(cnt, __ATOMIC_RELAXED,
                                         __HIP_MEMORY_SCOPE_AGENT) < tgt) {}
            }
            __syncthreads();
            asm volatile("" ::: "memory");   // no hoisting loads above the wait
        }
    }
}

// ---------------------------------------------------------------------------
extern "C" void kernel_launch(void* const* d_in, const int* in_sizes, int n_in,
                              void* d_out, int out_size, void* d_ws, size_t ws_size,
                              hipStream_t stream) {
    const float* x    = (const float*)d_in[0];  // (T, B, INSZ)
    const float* Win  = (const float*)d_in[1];  // (N, INSZ)
    const float* bias = (const float*)d_in[2];  // (N,)
    const float* Wlsm = (const float*)d_in[3];  // (N, N)
    float* out    = (float*)d_out;              // (T, B, N)
    unsigned* cnt = (unsigned*)d_ws;

    // Phase 1: input projection for all timesteps at once
    proj_kernel<<<dim3(16, (T_STEPS * BATCH) / TM), 256, 0, stream>>>(x, Win, bias, out);

    // Phase 2: single persistent cooperative kernel for all 1000 steps
    (void)hipMemsetAsync(d_ws, 0, NCLUST * 64 * sizeof(unsigned), stream);
    void* args[] = { (void*)&Wlsm, (void*)&out, (void*)&cnt };
    (void)hipLaunchCooperativeKernel((void*)lsm_persist,
                                     dim3(NCLUST * SLICES), dim3(PTH),
                                     args, 0, stream);
}